// Round 2
// baseline (588.840 us; speedup 1.0000x reference)
//
#include <hip/hip_runtime.h>
#include <hip/hip_bf16.h>

// Problem constants
constexpr int Bn   = 512;   // batch
constexpr int SK   = 128;   // K seq len (== BLOCK)
constexpr int SV   = 261;   // V seq len
constexpr int Dd   = 768;   // feature dim
constexpr int Hh   = 58;    // head dim for Q/K projections
constexpr int OUTn = 512;   // output dim of Vt
constexpr int IMG  = 197;
constexpr int Mrows = Bn * SV;               // 133632
constexpr long long CTX_ELEMS = (long long)Mrows * OUTn; // 68,419,584

// ws layout (bytes)
constexpr size_t WS_U   = 0;                       // 512*768 f32 = 1,572,864
constexpr size_t WS_C   = 1572864;                 // 512 f32
constexpr size_t WS_HOT = 1574912;                 // 512 f32
constexpr size_t WS_WB  = 1576960;                 // 512*768 bf16 = 786,432 (16B aligned)

typedef __attribute__((ext_vector_type(8))) short short8;
typedef __attribute__((ext_vector_type(4))) float floatx4;

__device__ __forceinline__ short f2bf(float f) {
    return __builtin_bit_cast(short, __float2bfloat16(f));
}

__device__ __forceinline__ float sigmoidf_(float x) {
    return 1.0f / (1.0f + __expf(-x));
}

// ---------------- Kernel A: Qt + u + c per batch ----------------
__global__ void __launch_bounds__(256) qt_u_kernel(
    const float* __restrict__ Q, const float* __restrict__ Wq, const float* __restrict__ bq,
    const float* __restrict__ Wk, const float* __restrict__ bk,
    float* __restrict__ u, float* __restrict__ c)
{
    int b = blockIdx.x;
    int t = threadIdx.x, lane = t & 63, w = t >> 6; // 4 waves

    __shared__ float qrow[Dd];
    __shared__ float qt[Hh];

    for (int d = t; d < Dd; d += 256) qrow[d] = Q[b * Dd + d];
    __syncthreads();

    for (int h = w; h < Hh; h += 4) {
        const float* wr = Wq + (size_t)h * Dd;
        float s = 0.f;
        #pragma unroll
        for (int j = 0; j < 12; ++j) { int d = lane + 64 * j; s += qrow[d] * wr[d]; }
        #pragma unroll
        for (int off = 32; off; off >>= 1) s += __shfl_down(s, off);
        if (lane == 0) qt[h] = s + bq[h];
    }
    __syncthreads();

    for (int d = t; d < Dd; d += 256) {
        float s = 0.f;
        #pragma unroll 2
        for (int h = 0; h < Hh; ++h) s += qt[h] * Wk[(size_t)h * Dd + d];
        u[(size_t)b * Dd + d] = s;
    }

    if (w == 0) {
        float v = (lane < Hh) ? qt[lane] * bk[lane] : 0.f;
        #pragma unroll
        for (int off = 32; off; off >>= 1) v += __shfl_down(v, off);
        if (lane == 0) c[b] = v;
    }
}

// ---------------- Kernel B: scores -> attn (out) + hot ----------------
__global__ void __launch_bounds__(512) scores_kernel(
    const float* __restrict__ K, const float* __restrict__ u, const float* __restrict__ c,
    const float* __restrict__ Wsw, const float* __restrict__ bsw,
    float* __restrict__ attn_out, float* __restrict__ hot)
{
    int b = blockIdx.x;
    int t = threadIdx.x, lane = t & 63, w = t >> 6; // 8 waves

    __shared__ float ul[Dd];
    __shared__ float al[SK];

    for (int d = t; d < Dd; d += 512) ul[d] = u[(size_t)b * Dd + d];
    float cb = c[b];
    __syncthreads();

    const float* Kb = K + (size_t)b * SK * Dd;
    for (int k = w; k < SK; k += 8) {
        const float* kr = Kb + (size_t)k * Dd;
        float s = 0.f;
        #pragma unroll
        for (int j = 0; j < 12; ++j) { int d = lane + 64 * j; s += kr[d] * ul[d]; }
        #pragma unroll
        for (int off = 32; off; off >>= 1) s += __shfl_down(s, off);
        if (lane == 0) {
            float sc = (s + cb) * 0.0883883476483184f; // 1/sqrt(128)
            float a = sigmoidf_(sc);
            attn_out[(size_t)b * SK + k] = a;
            al[k] = a;
        }
    }
    __syncthreads();

    if (w == 0) {
        float v = al[lane] * Wsw[lane] + al[lane + 64] * Wsw[lane + 64];
        #pragma unroll
        for (int off = 32; off; off >>= 1) v += __shfl_down(v, off);
        if (lane == 0) hot[b] = sigmoidf_(v + bsw[0]);
    }
}

// ---------------- Kernel D: Wv f32 -> bf16, MFMA-fragment-major layout ----------------
// Chunk index = kb*32 + g  (g = col>>4), 768 chunks of 1KB.
// Within chunk: lane = ((k>>3)&3)*16 + (col&15), 8 consecutive bf16 k's per lane.
// => fragment (kb, col-group) is one coalesced dwordx4 load per wave.
__global__ void __launch_bounds__(256) wv_convert(
    const float* __restrict__ Wv, unsigned short* __restrict__ wsB)
{
    int t = blockIdx.x * 256 + threadIdx.x;
    if (t >= OUTn * Dd) return;
    int col = t / Dd;
    int k   = t - col * Dd;
    int kb = k >> 5, kgrp = (k >> 3) & 3, kj = k & 7;
    int g = col >> 4, cl = col & 15;
    size_t off = ((size_t)(kb * 32 + g) * 64 + (kgrp * 16 + cl)) * 8 + kj;
    wsB[off] = (unsigned short)f2bf(Wv[t]);
}

// ---------------- Kernel C: context = scale(b,s) * (V·Wv^T + bv) ----------------
// Barrier-free, LDS-free. 256 threads = 4 waves (1m x 4n), wave tile 64x64.
// A (V, f32) and B (wsB, bf16 fragments) loaded straight to registers with a
// one-K-step software prefetch; all 4 waves read identical A addresses -> L1.
__global__ void __launch_bounds__(256, 3) ctx_gemm(
    const float* __restrict__ V, const unsigned short* __restrict__ wsB,
    const float* __restrict__ bv, const float* __restrict__ hot,
    float* __restrict__ out)
{
    int bid = blockIdx.x;
    int nt = bid & 1;          // adjacent bids share A rows (L2/L3 reuse)
    int mt = bid >> 1;
    int t = threadIdx.x, lane = t & 63, wn = t >> 6;

    const float* aB = V + (size_t)(mt * 64 + (lane & 15)) * Dd + ((lane >> 4) * 8);
    const unsigned short* bB = wsB + ((size_t)(nt * 16 + wn * 4) * 64 + lane) * 8;

    floatx4 acc[4][4] = {};
    float4 pa[8];
    short8 pb[4];

    auto loadA = [&](int kb) {
        #pragma unroll
        for (int mr = 0; mr < 4; ++mr) {
            const float4* p = (const float4*)(aB + (size_t)mr * 16 * Dd + kb * 32);
            pa[2 * mr]     = p[0];
            pa[2 * mr + 1] = p[1];
        }
    };
    auto loadB = [&](int kb) {
        #pragma unroll
        for (int nr = 0; nr < 4; ++nr)
            pb[nr] = *(const short8*)(bB + (size_t)(kb * 32 + nr) * 512);
    };

    loadA(0);
    loadB(0);

    #pragma unroll
    for (int kb = 0; kb < 24; ++kb) {
        // consume prefetched regs (compiler inserts precise vmcnt)
        short8 af[4];
        #pragma unroll
        for (int mr = 0; mr < 4; ++mr) {
            float4 f0 = pa[2 * mr], f1 = pa[2 * mr + 1];
            short8 a;
            a[0] = f2bf(f0.x); a[1] = f2bf(f0.y); a[2] = f2bf(f0.z); a[3] = f2bf(f0.w);
            a[4] = f2bf(f1.x); a[5] = f2bf(f1.y); a[6] = f2bf(f1.z); a[7] = f2bf(f1.w);
            af[mr] = a;
        }
        short8 bf[4];
        #pragma unroll
        for (int nr = 0; nr < 4; ++nr) bf[nr] = pb[nr];

        // issue next K-step's loads BEFORE the MFMA cluster (A first: HBM latency)
        if (kb + 1 < 24) { loadA(kb + 1); loadB(kb + 1); }

        #pragma unroll
        for (int mr = 0; mr < 4; ++mr)
            #pragma unroll
            for (int nr = 0; nr < 4; ++nr)
                acc[mr][nr] = __builtin_amdgcn_mfma_f32_16x16x32_bf16(af[mr], bf[nr], acc[mr][nr], 0, 0, 0);
    }

    // Epilogue: out[m,n] = scale(b,s) * (acc + bv[n]); C/D: col=lane&15, row=(lane>>4)*4+reg
    float bvv[4];
    #pragma unroll
    for (int nr = 0; nr < 4; ++nr)
        bvv[nr] = bv[nt * 256 + wn * 64 + nr * 16 + (lane & 15)];

    int ncol0 = nt * 256 + wn * 64 + (lane & 15);
    #pragma unroll
    for (int mr = 0; mr < 4; ++mr) {
        #pragma unroll
        for (int rg = 0; rg < 4; ++rg) {
            int m = mt * 64 + mr * 16 + ((lane >> 4) << 2) + rg;
            int b = m / 261;
            int s = m - b * 261;
            float h = hot[b];
            float scale = (s < IMG) ? h : (1.0f - h);
            float* orow = out + (size_t)m * OUTn + ncol0;
            #pragma unroll
            for (int nr = 0; nr < 4; ++nr)
                orow[nr * 16] = scale * (acc[mr][nr][rg] + bvv[nr]);
        }
    }
}

extern "C" void kernel_launch(void* const* d_in, const int* in_sizes, int n_in,
                              void* d_out, int out_size, void* d_ws, size_t ws_size,
                              hipStream_t stream) {
    const float* Q   = (const float*)d_in[0];
    const float* K   = (const float*)d_in[1];
    const float* V   = (const float*)d_in[2];
    const float* Wq  = (const float*)d_in[3];
    const float* bq  = (const float*)d_in[4];
    const float* Wk  = (const float*)d_in[5];
    const float* bk  = (const float*)d_in[6];
    const float* Wsw = (const float*)d_in[7];
    const float* bsw = (const float*)d_in[8];
    const float* Wv  = (const float*)d_in[9];
    const float* bv  = (const float*)d_in[10];

    float* out = (float*)d_out;
    char* ws = (char*)d_ws;
    float* u   = (float*)(ws + WS_U);
    float* c   = (float*)(ws + WS_C);
    float* hot = (float*)(ws + WS_HOT);
    unsigned short* wsB = (unsigned short*)(ws + WS_WB);

    hipLaunchKernelGGL(wv_convert, dim3((OUTn * Dd + 255) / 256), dim3(256), 0, stream, Wv, wsB);
    hipLaunchKernelGGL(qt_u_kernel, dim3(Bn), dim3(256), 0, stream, Q, Wq, bq, Wk, bk, u, c);
    hipLaunchKernelGGL(scores_kernel, dim3(Bn), dim3(512), 0, stream,
                       K, u, c, Wsw, bsw, out + CTX_ELEMS, hot);
    hipLaunchKernelGGL(ctx_gemm, dim3((Mrows / 64) * 2), dim3(256), 0, stream, V, wsB, bv, hot, out);
}

// Round 3
// 327.518 us; speedup vs baseline: 1.7979x; 1.7979x over previous
//
#include <hip/hip_runtime.h>
#include <hip/hip_bf16.h>

// Problem constants
constexpr int Bn   = 512;   // batch
constexpr int SK   = 128;   // K seq len (== BLOCK)
constexpr int SV   = 261;   // V seq len
constexpr int Dd   = 768;   // feature dim
constexpr int Hh   = 58;    // head dim for Q/K projections
constexpr int OUTn = 512;   // output dim of Vt
constexpr int IMG  = 197;
constexpr int Mrows = Bn * SV;               // 133632
constexpr long long CTX_ELEMS = (long long)Mrows * OUTn; // 68,419,584

// ws layout (bytes)
constexpr size_t WS_U   = 0;                       // 512*768 f32
constexpr size_t WS_C   = 1572864;                 // 512 f32
constexpr size_t WS_HOT = 1574912;                 // 512 f32
constexpr size_t WS_WB  = 1576960;                 // 512*768 bf16

typedef __attribute__((ext_vector_type(8))) short short8;
typedef __attribute__((ext_vector_type(4))) float floatx4;

__device__ __forceinline__ short f2bf(float f) {
    return __builtin_bit_cast(short, __float2bfloat16(f));
}

__device__ __forceinline__ float sigmoidf_(float x) {
    return 1.0f / (1.0f + __expf(-x));
}

template <int N>
__device__ __forceinline__ void wait_vm() {
    asm volatile("s_waitcnt vmcnt(%0)" :: "n"(N) : "memory");
}

template <int OFF>
__device__ __forceinline__ floatx4 ds_read128(unsigned addr) {
    floatx4 r;
    asm volatile("ds_read_b128 %0, %1 offset:%2" : "=v"(r) : "v"(addr), "n"(OFF));
    return r;
}

__device__ __forceinline__ void lds_dma16(const float* src, float* dst) {
    __builtin_amdgcn_global_load_lds(
        (const __attribute__((address_space(1))) void*)src,
        (__attribute__((address_space(3))) void*)dst,
        16, 0, 0);
}

// ---------------- Kernel A: Qt + u + c per batch ----------------
__global__ void __launch_bounds__(256) qt_u_kernel(
    const float* __restrict__ Q, const float* __restrict__ Wq, const float* __restrict__ bq,
    const float* __restrict__ Wk, const float* __restrict__ bk,
    float* __restrict__ u, float* __restrict__ c)
{
    int b = blockIdx.x;
    int t = threadIdx.x, lane = t & 63, w = t >> 6; // 4 waves

    __shared__ float qrow[Dd];
    __shared__ float qt[Hh];

    for (int d = t; d < Dd; d += 256) qrow[d] = Q[b * Dd + d];
    __syncthreads();

    for (int h = w; h < Hh; h += 4) {
        const float* wr = Wq + (size_t)h * Dd;
        float s = 0.f;
        #pragma unroll
        for (int j = 0; j < 12; ++j) { int d = lane + 64 * j; s += qrow[d] * wr[d]; }
        #pragma unroll
        for (int off = 32; off; off >>= 1) s += __shfl_down(s, off);
        if (lane == 0) qt[h] = s + bq[h];
    }
    __syncthreads();

    for (int d = t; d < Dd; d += 256) {
        float s = 0.f;
        #pragma unroll 2
        for (int h = 0; h < Hh; ++h) s += qt[h] * Wk[(size_t)h * Dd + d];
        u[(size_t)b * Dd + d] = s;
    }

    if (w == 0) {
        float v = (lane < Hh) ? qt[lane] * bk[lane] : 0.f;
        #pragma unroll
        for (int off = 32; off; off >>= 1) v += __shfl_down(v, off);
        if (lane == 0) c[b] = v;
    }
}

// ---------------- Kernel B: scores -> attn (out) + hot ----------------
__global__ void __launch_bounds__(512) scores_kernel(
    const float* __restrict__ K, const float* __restrict__ u, const float* __restrict__ c,
    const float* __restrict__ Wsw, const float* __restrict__ bsw,
    float* __restrict__ attn_out, float* __restrict__ hot)
{
    int b = blockIdx.x;
    int t = threadIdx.x, lane = t & 63, w = t >> 6; // 8 waves

    __shared__ float ul[Dd];
    __shared__ float al[SK];

    for (int d = t; d < Dd; d += 512) ul[d] = u[(size_t)b * Dd + d];
    float cb = c[b];
    __syncthreads();

    const float* Kb = K + (size_t)b * SK * Dd;
    for (int k = w; k < SK; k += 8) {
        const float* kr = Kb + (size_t)k * Dd;
        float s = 0.f;
        #pragma unroll
        for (int j = 0; j < 12; ++j) { int d = lane + 64 * j; s += kr[d] * ul[d]; }
        #pragma unroll
        for (int off = 32; off; off >>= 1) s += __shfl_down(s, off);
        if (lane == 0) {
            float sc = (s + cb) * 0.0883883476483184f; // 1/sqrt(128)
            float a = sigmoidf_(sc);
            attn_out[(size_t)b * SK + k] = a;
            al[k] = a;
        }
    }
    __syncthreads();

    if (w == 0) {
        float v = al[lane] * Wsw[lane] + al[lane + 64] * Wsw[lane + 64];
        #pragma unroll
        for (int off = 32; off; off >>= 1) v += __shfl_down(v, off);
        if (lane == 0) hot[b] = sigmoidf_(v + bsw[0]);
    }
}

// ---------------- Kernel D: Wv f32 -> bf16, MFMA-fragment-major layout ----------------
__global__ void __launch_bounds__(256) wv_convert(
    const float* __restrict__ Wv, unsigned short* __restrict__ wsB)
{
    int t = blockIdx.x * 256 + threadIdx.x;
    if (t >= OUTn * Dd) return;
    int col = t / Dd;
    int k   = t - col * Dd;
    int kb = k >> 5, kgrp = (k >> 3) & 3, kj = k & 7;
    int g = col >> 4, cl = col & 15;
    size_t off = ((size_t)(kb * 32 + g) * 64 + (kgrp * 16 + cl)) * 8 + kj;
    wsB[off] = (unsigned short)f2bf(Wv[t]);
}

// ---------------- Kernel C: context = scale(b,s) * (V·Wv^T + bv) ----------------
// BM=64, BN=256, 256 thr = 4 waves (wave tile 64x64). A: global_load_lds DMA into
// triple-buffered LDS (source pre-swizzled, ds_read swizzled -> conflict-free).
// B: L2-resident fragment-major ws, reg double-buffered. Counted vmcnt, raw barriers.
__global__ void __launch_bounds__(256, 2) ctx_gemm(
    const float* __restrict__ V, const unsigned short* __restrict__ wsB,
    const float* __restrict__ bv, const float* __restrict__ hot,
    float* __restrict__ out)
{
    int bid = blockIdx.x;
    int nt = bid & 1;          // adjacent bids share A rows (L2 absorbs dup fetch)
    int mt = bid >> 1;
    int t = threadIdx.x, lane = t & 63, w = t >> 6;
    int m_base = mt * 64;

    __shared__ float ldsA[3][2048];   // 3 x 8KB (64 rows x 32 f32)

    // DMA source: per-lane global addr pre-swizzled so LDS (written linearly)
    // holds granule g at phys (g ^ (row&7)).
    int r8 = lane >> 3;                         // 0..7 (row within 8-row group)
    int glog = (lane & 7) ^ r8;                 // logical 16B granule to fetch
    const float* srcJ0 = V + (size_t)(m_base + w * 16 + r8) * Dd + glog * 4;
    const float* srcJ1 = srcJ0 + (size_t)8 * Dd;
    const int rb0 = (w * 16) * 32;              // LDS float index of row block 0
    const int rb1 = (w * 16 + 8) * 32;

    // ds_read addresses (byte): row*128 + ((g ^ (row&7))<<4)
    __attribute__((address_space(3))) float* l3 =
        (__attribute__((address_space(3))) float*)&ldsA[0][0];
    unsigned ldsBase = (unsigned)(unsigned long long)l3;
    int r0 = lane & 15;
    int g0 = (lane >> 4) * 2;
    unsigned adr0[4], adr1[4];
    #pragma unroll
    for (int mr = 0; mr < 4; ++mr) {
        int row = mr * 16 + r0;
        adr0[mr] = ldsBase + row * 128 + (unsigned)((g0 ^ (row & 7)) << 4);
        adr1[mr] = ldsBase + row * 128 + (unsigned)(((g0 + 1) ^ (row & 7)) << 4);
    }

    const unsigned short* bB = wsB + ((size_t)(nt * 16 + w * 4) * 64 + lane) * 8;

    floatx4 acc[4][4] = {};
    short8 pbA[4], pbB[4];

    // Prologue: stage(0), stage(1), loadB(0); retire stage(0); barrier.
    lds_dma16(srcJ0, &ldsA[0][rb0]);
    lds_dma16(srcJ1, &ldsA[0][rb1]);
    lds_dma16(srcJ0 + 32, &ldsA[1][rb0]);
    lds_dma16(srcJ1 + 32, &ldsA[1][rb1]);
    #pragma unroll
    for (int nr = 0; nr < 4; ++nr) pbA[nr] = *(const short8*)(bB + (size_t)nr * 512);
    wait_vm<6>();
    __builtin_amdgcn_s_barrier();

// Per K-step: stage(T+2) DMA | loadB(T+1) | ds_read(T) | cvt | vmcnt | 16 MFMA | barrier.
// vmcnt ledger (per wave, issue order stage x2 then loadB x4):
//   steady: in-flight [s(T+1) x2, b(T) x4, s(T+2) x2, b(T+1) x4] -> vmcnt(6)
//   T=22 (no stage): vmcnt(4); T=23 (nothing issued): vmcnt(0).
#define KSTEP(T, BUF, PBC, PBN, VM, DOSTAGE, DOLOADB)                              \
  {                                                                                \
    if (DOSTAGE) {                                                                 \
      lds_dma16(srcJ0 + (size_t)((T) + 2) * 32, &ldsA[((T) + 2) % 3][rb0]);        \
      lds_dma16(srcJ1 + (size_t)((T) + 2) * 32, &ldsA[((T) + 2) % 3][rb1]);        \
    }                                                                              \
    __builtin_amdgcn_sched_barrier(0);                                             \
    if (DOLOADB) {                                                                 \
      _Pragma("unroll")                                                            \
      for (int nr = 0; nr < 4; ++nr)                                               \
        PBN[nr] = *(const short8*)(bB + ((size_t)((T) + 1) * 32 + nr) * 512);      \
    }                                                                              \
    __builtin_amdgcn_sched_barrier(0);                                             \
    floatx4 fr[8];                                                                 \
    _Pragma("unroll")                                                              \
    for (int mr = 0; mr < 4; ++mr) {                                               \
      fr[2 * mr]     = ds_read128<(BUF) * 8192>(adr0[mr]);                         \
      fr[2 * mr + 1] = ds_read128<(BUF) * 8192>(adr1[mr]);                         \
    }                                                                              \
    asm volatile("s_waitcnt lgkmcnt(0)" ::: "memory");                             \
    __builtin_amdgcn_sched_barrier(0);                                             \
    short8 af[4];                                                                  \
    _Pragma("unroll")                                                              \
    for (int mr = 0; mr < 4; ++mr) {                                               \
      floatx4 f0 = fr[2 * mr], f1 = fr[2 * mr + 1];                                \
      af[mr][0] = f2bf(f0[0]); af[mr][1] = f2bf(f0[1]);                            \
      af[mr][2] = f2bf(f0[2]); af[mr][3] = f2bf(f0[3]);                            \
      af[mr][4] = f2bf(f1[0]); af[mr][5] = f2bf(f1[1]);                            \
      af[mr][6] = f2bf(f1[2]); af[mr][7] = f2bf(f1[3]);                            \
    }                                                                              \
    wait_vm<VM>();                                                                 \
    __builtin_amdgcn_sched_barrier(0);                                             \
    _Pragma("unroll")                                                              \
    for (int mr = 0; mr < 4; ++mr) {                                               \
      _Pragma("unroll")                                                            \
      for (int nr = 0; nr < 4; ++nr)                                               \
        acc[mr][nr] = __builtin_amdgcn_mfma_f32_16x16x32_bf16(af[mr], PBC[nr],     \
                                                              acc[mr][nr], 0, 0, 0);\
    }                                                                              \
    __builtin_amdgcn_s_barrier();                                                  \
  }

    for (int tb = 0; tb < 3; ++tb) {
        int T0 = tb * 6;
        KSTEP(T0 + 0, 0, pbA, pbB, 6, 1, 1)
        KSTEP(T0 + 1, 1, pbB, pbA, 6, 1, 1)
        KSTEP(T0 + 2, 2, pbA, pbB, 6, 1, 1)
        KSTEP(T0 + 3, 0, pbB, pbA, 6, 1, 1)
        KSTEP(T0 + 4, 1, pbA, pbB, 6, 1, 1)
        KSTEP(T0 + 5, 2, pbB, pbA, 6, 1, 1)
    }
    KSTEP(18, 0, pbA, pbB, 6, 1, 1)
    KSTEP(19, 1, pbB, pbA, 6, 1, 1)
    KSTEP(20, 2, pbA, pbB, 6, 1, 1)
    KSTEP(21, 0, pbB, pbA, 6, 1, 1)
    KSTEP(22, 1, pbA, pbB, 4, 0, 1)
    KSTEP(23, 2, pbB, pbA, 0, 0, 0)
#undef KSTEP

    // Epilogue: out[m,n] = scale(b,s) * (acc + bv[n]); C/D: col=lane&15, row=(lane>>4)*4+reg
    float bvv[4];
    #pragma unroll
    for (int nr = 0; nr < 4; ++nr)
        bvv[nr] = bv[nt * 256 + w * 64 + nr * 16 + (lane & 15)];

    int ncol0 = nt * 256 + w * 64 + (lane & 15);
    #pragma unroll
    for (int mr = 0; mr < 4; ++mr) {
        #pragma unroll
        for (int rg = 0; rg < 4; ++rg) {
            int m = m_base + mr * 16 + ((lane >> 4) << 2) + rg;
            int b = m / 261;
            int s = m - b * 261;
            float h = hot[b];
            float scale = (s < IMG) ? h : (1.0f - h);
            float* orow = out + (size_t)m * OUTn + ncol0;
            #pragma unroll
            for (int nr = 0; nr < 4; ++nr)
                orow[nr * 16] = scale * (acc[mr][nr][rg] + bvv[nr]);
        }
    }
}

extern "C" void kernel_launch(void* const* d_in, const int* in_sizes, int n_in,
                              void* d_out, int out_size, void* d_ws, size_t ws_size,
                              hipStream_t stream) {
    const float* Q   = (const float*)d_in[0];
    const float* K   = (const float*)d_in[1];
    const float* V   = (const float*)d_in[2];
    const float* Wq  = (const float*)d_in[3];
    const float* bq  = (const float*)d_in[4];
    const float* Wk  = (const float*)d_in[5];
    const float* bk  = (const float*)d_in[6];
    const float* Wsw = (const float*)d_in[7];
    const float* bsw = (const float*)d_in[8];
    const float* Wv  = (const float*)d_in[9];
    const float* bv  = (const float*)d_in[10];

    float* out = (float*)d_out;
    char* ws = (char*)d_ws;
    float* u   = (float*)(ws + WS_U);
    float* c   = (float*)(ws + WS_C);
    float* hot = (float*)(ws + WS_HOT);
    unsigned short* wsB = (unsigned short*)(ws + WS_WB);

    hipLaunchKernelGGL(wv_convert, dim3((OUTn * Dd + 255) / 256), dim3(256), 0, stream, Wv, wsB);
    hipLaunchKernelGGL(qt_u_kernel, dim3(Bn), dim3(256), 0, stream, Q, Wq, bq, Wk, bk, u, c);
    hipLaunchKernelGGL(scores_kernel, dim3(Bn), dim3(512), 0, stream,
                       K, u, c, Wsw, bsw, out + CTX_ELEMS, hot);
    hipLaunchKernelGGL(ctx_gemm, dim3((Mrows / 64) * 2), dim3(256), 0, stream, V, wsB, bv, hot, out);
}

// Round 4
// 298.724 us; speedup vs baseline: 1.9712x; 1.0964x over previous
//
#include <hip/hip_runtime.h>
#include <hip/hip_bf16.h>

// Problem constants
constexpr int Bn   = 512;   // batch
constexpr int SK   = 128;   // K seq len (== BLOCK)
constexpr int SV   = 261;   // V seq len
constexpr int Dd   = 768;   // feature dim
constexpr int Hh   = 58;    // head dim for Q/K projections
constexpr int OUTn = 512;   // output dim of Vt
constexpr int IMG  = 197;
constexpr int Mrows = Bn * SV;               // 133632
constexpr long long CTX_ELEMS = (long long)Mrows * OUTn; // 68,419,584

// ws layout (bytes)
constexpr size_t WS_HOT = 0;        // 512 f32
constexpr size_t WS_WB  = 4096;     // 512*768 bf16

typedef __attribute__((ext_vector_type(8))) short short8;
typedef __attribute__((ext_vector_type(4))) float floatx4;

__device__ __forceinline__ short f2bf(float f) {
    return __builtin_bit_cast(short, __float2bfloat16(f));
}

__device__ __forceinline__ float sigmoidf_(float x) {
    return 1.0f / (1.0f + __expf(-x));
}

template <int N>
__device__ __forceinline__ void wait_vm() {
    asm volatile("s_waitcnt vmcnt(%0)" :: "n"(N) : "memory");
}

template <int OFF>
__device__ __forceinline__ floatx4 ds_read128(unsigned addr) {
    floatx4 r;
    asm volatile("ds_read_b128 %0, %1 offset:%2" : "=v"(r) : "v"(addr), "n"(OFF));
    return r;
}

__device__ __forceinline__ void lds_dma16(const float* src, float* dst) {
    __builtin_amdgcn_global_load_lds(
        (const __attribute__((address_space(1))) void*)src,
        (__attribute__((address_space(3))) void*)dst,
        16, 0, 0);
}

// ---------------- Kernel B: fused Qt/u/c + scores -> attn (out) + hot ----------------
__global__ void __launch_bounds__(512) scores_fused(
    const float* __restrict__ Q, const float* __restrict__ K,
    const float* __restrict__ Wq, const float* __restrict__ bq,
    const float* __restrict__ Wk, const float* __restrict__ bk,
    const float* __restrict__ Wsw, const float* __restrict__ bsw,
    float* __restrict__ attn_out, float* __restrict__ hot)
{
    int b = blockIdx.x;
    int t = threadIdx.x, lane = t & 63, w = t >> 6; // 8 waves

    __shared__ __align__(16) float qrow[Dd];
    __shared__ float qt[64];
    __shared__ __align__(16) float ul[Dd];
    __shared__ float al[SK];
    __shared__ float cbs;

    qrow[t] = Q[b * Dd + t];
    if (t < Dd - 512) qrow[t + 512] = Q[b * Dd + t + 512];
    __syncthreads();

    // qt[h] = Q[b]·Wq[h] + bq[h]
    for (int h = w; h < Hh; h += 8) {
        const float4* wr4 = (const float4*)(Wq + (size_t)h * Dd);
        const float4* q4  = (const float4*)qrow;
        float s = 0.f;
        #pragma unroll
        for (int j = 0; j < 3; ++j) {
            float4 a = q4[lane + 64 * j], c = wr4[lane + 64 * j];
            s += a.x * c.x + a.y * c.y + a.z * c.z + a.w * c.w;
        }
        #pragma unroll
        for (int off = 32; off; off >>= 1) s += __shfl_down(s, off);
        if (lane == 0) qt[h] = s + bq[h];
    }
    __syncthreads();

    // u[d] = sum_h qt[h]*Wk[h,d] ; c = qt·bk
    for (int d = t; d < Dd; d += 512) {
        float s = 0.f;
        #pragma unroll 2
        for (int h = 0; h < Hh; ++h) s += qt[h] * Wk[(size_t)h * Dd + d];
        ul[d] = s;
    }
    if (w == 0) {
        float v = (lane < Hh) ? qt[lane] * bk[lane] : 0.f;
        #pragma unroll
        for (int off = 32; off; off >>= 1) v += __shfl_down(v, off);
        if (lane == 0) cbs = v;
    }
    __syncthreads();

    float cb = cbs;
    const float4* Kb4 = (const float4*)(K + (size_t)b * SK * Dd);
    const float4* u4  = (const float4*)ul;
    for (int k = w; k < SK; k += 8) {
        const float4* kr4 = Kb4 + (size_t)k * (Dd / 4);
        float s = 0.f;
        #pragma unroll
        for (int j = 0; j < 3; ++j) {
            float4 a = kr4[lane + 64 * j], c = u4[lane + 64 * j];
            s += a.x * c.x + a.y * c.y + a.z * c.z + a.w * c.w;
        }
        #pragma unroll
        for (int off = 32; off; off >>= 1) s += __shfl_down(s, off);
        if (lane == 0) {
            float sc = (s + cb) * 0.0883883476483184f; // 1/sqrt(128)
            float a = sigmoidf_(sc);
            attn_out[(size_t)b * SK + k] = a;
            al[k] = a;
        }
    }
    __syncthreads();

    if (w == 0) {
        float v = al[lane] * Wsw[lane] + al[lane + 64] * Wsw[lane + 64];
        #pragma unroll
        for (int off = 32; off; off >>= 1) v += __shfl_down(v, off);
        if (lane == 0) hot[b] = sigmoidf_(v + bsw[0]);
    }
}

// ---------------- Kernel D: Wv f32 -> bf16, MFMA-fragment-major layout ----------------
__global__ void __launch_bounds__(256) wv_convert(
    const float* __restrict__ Wv, unsigned short* __restrict__ wsB)
{
    int t = blockIdx.x * 256 + threadIdx.x;
    if (t >= OUTn * Dd) return;
    int col = t / Dd;
    int k   = t - col * Dd;
    int kb = k >> 5, kgrp = (k >> 3) & 3, kj = k & 7;
    int g = col >> 4, cl = col & 15;
    size_t off = ((size_t)(kb * 32 + g) * 64 + (kgrp * 16 + cl)) * 8 + kj;
    wsB[off] = (unsigned short)f2bf(Wv[t]);
}

// ---------------- Kernel C: context = scale(b,s) * (V·Wv^T + bv) ----------------
// BM=64, BN=256, 4 waves. A: global_load_lds DMA, QUAD-buffered LDS, staged 3 steps
// ahead (s(T+3) at step T) -> ~2 full K-steps of HBM latency cover. B: L2-resident
// fragment loads issued 1 step ahead, BEFORE the A-stage so counted vmcnt retires
// b(T) without touching young stages. Raw barriers; never vmcnt(0) mid-loop.
__global__ void __launch_bounds__(256, 3) ctx_gemm(
    const float* __restrict__ V, const unsigned short* __restrict__ wsB,
    const float* __restrict__ bv, const float* __restrict__ hot,
    float* __restrict__ out)
{
    // XCD swizzle: 4176 blocks = 8 * 522; keep nt-pairs (same A rows) on one XCD.
    int bid = (blockIdx.x >> 3) + (blockIdx.x & 7) * 522;
    int nt = bid & 1;
    int mt = bid >> 1;
    int t = threadIdx.x, lane = t & 63, w = t >> 6;
    int m_base = mt * 64;

    __shared__ float ldsA[4][2048];   // 4 x 8KB (64 rows x 32 f32)

    // DMA source pre-swizzled: LDS (written linearly) holds granule g at phys g^(row&7).
    int r8 = lane >> 3;
    int glog = (lane & 7) ^ r8;
    const float* srcJ0 = V + (size_t)(m_base + w * 16 + r8) * Dd + glog * 4;
    const float* srcJ1 = srcJ0 + (size_t)8 * Dd;
    const int rb0 = (w * 16) * 32;
    const int rb1 = (w * 16 + 8) * 32;

    __attribute__((address_space(3))) float* l3 =
        (__attribute__((address_space(3))) float*)&ldsA[0][0];
    unsigned ldsBase = (unsigned)(unsigned long long)l3;
    int r0 = lane & 15;
    int g0 = (lane >> 4) * 2;
    unsigned adr0[4], adr1[4];
    #pragma unroll
    for (int mr = 0; mr < 4; ++mr) {
        int row = mr * 16 + r0;
        adr0[mr] = ldsBase + row * 128 + (unsigned)((g0 ^ (row & 7)) << 4);
        adr1[mr] = ldsBase + row * 128 + (unsigned)(((g0 + 1) ^ (row & 7)) << 4);
    }

    const unsigned short* bB = wsB + ((size_t)(nt * 16 + w * 4) * 64 + lane) * 8;

    floatx4 acc[4][4] = {};
    short8 pbA[4], pbB[4];

    // Prologue: stage bufs 0,1,2; load b(0). Ledger: [s0 s1 s2 b0]=10 -> vm(8) retires s0.
    lds_dma16(srcJ0, &ldsA[0][rb0]);
    lds_dma16(srcJ1, &ldsA[0][rb1]);
    lds_dma16(srcJ0 + 32, &ldsA[1][rb0]);
    lds_dma16(srcJ1 + 32, &ldsA[1][rb1]);
    lds_dma16(srcJ0 + 64, &ldsA[2][rb0]);
    lds_dma16(srcJ1 + 64, &ldsA[2][rb1]);
    #pragma unroll
    for (int nr = 0; nr < 4; ++nr) pbA[nr] = *(const short8*)(bB + (size_t)nr * 512);
    wait_vm<8>();
    __builtin_amdgcn_s_barrier();

// Step T: loadB(T+1) | stage(T+3) | ds_read(T) | lgkm | cvt | vmcnt | 16 MFMA b(T) | barrier.
// Steady ledger: entry [s(T+1)x2 b(T)x4 s(T+2)x2] + issue [b(T+1)x4 s(T+3)x2] = 14;
// vm(8) retires s(T+1),b(T).  T=0: vm(6).  Tail T=21/22/23: vm(6)/(4)/(0).
#define KSTEP(T, PBC, PBN, VM, DOSTAGE, DOLOADB)                                   \
  {                                                                                \
    if (DOLOADB) {                                                                 \
      _Pragma("unroll")                                                            \
      for (int nr = 0; nr < 4; ++nr)                                               \
        PBN[nr] = *(const short8*)(bB + ((size_t)((T) + 1) * 32 + nr) * 512);      \
    }                                                                              \
    __builtin_amdgcn_sched_barrier(0);                                             \
    if (DOSTAGE) {                                                                 \
      lds_dma16(srcJ0 + (size_t)((T) + 3) * 32, &ldsA[((T) + 3) & 3][rb0]);        \
      lds_dma16(srcJ1 + (size_t)((T) + 3) * 32, &ldsA[((T) + 3) & 3][rb1]);        \
    }                                                                              \
    __builtin_amdgcn_sched_barrier(0);                                             \
    floatx4 fr[8];                                                                 \
    _Pragma("unroll")                                                              \
    for (int mr = 0; mr < 4; ++mr) {                                               \
      fr[2 * mr]     = ds_read128<((T) & 3) * 8192>(adr0[mr]);                     \
      fr[2 * mr + 1] = ds_read128<((T) & 3) * 8192>(adr1[mr]);                     \
    }                                                                              \
    asm volatile("s_waitcnt lgkmcnt(0)" ::: "memory");                             \
    __builtin_amdgcn_sched_barrier(0);                                             \
    short8 af[4];                                                                  \
    _Pragma("unroll")                                                              \
    for (int mr = 0; mr < 4; ++mr) {                                               \
      floatx4 f0 = fr[2 * mr], f1 = fr[2 * mr + 1];                                \
      af[mr][0] = f2bf(f0[0]); af[mr][1] = f2bf(f0[1]);                            \
      af[mr][2] = f2bf(f0[2]); af[mr][3] = f2bf(f0[3]);                            \
      af[mr][4] = f2bf(f1[0]); af[mr][5] = f2bf(f1[1]);                            \
      af[mr][6] = f2bf(f1[2]); af[mr][7] = f2bf(f1[3]);                            \
    }                                                                              \
    wait_vm<VM>();                                                                 \
    __builtin_amdgcn_sched_barrier(0);                                             \
    _Pragma("unroll")                                                              \
    for (int mr = 0; mr < 4; ++mr) {                                               \
      _Pragma("unroll")                                                            \
      for (int nr = 0; nr < 4; ++nr)                                               \
        acc[mr][nr] = __builtin_amdgcn_mfma_f32_16x16x32_bf16(af[mr], PBC[nr],     \
                                                              acc[mr][nr], 0, 0, 0);\
    }                                                                              \
    __builtin_amdgcn_s_barrier();                                                  \
  }

    KSTEP(0,  pbA, pbB, 6, 1, 1)
    KSTEP(1,  pbB, pbA, 8, 1, 1)
    KSTEP(2,  pbA, pbB, 8, 1, 1)
    KSTEP(3,  pbB, pbA, 8, 1, 1)
    KSTEP(4,  pbA, pbB, 8, 1, 1)
    KSTEP(5,  pbB, pbA, 8, 1, 1)
    KSTEP(6,  pbA, pbB, 8, 1, 1)
    KSTEP(7,  pbB, pbA, 8, 1, 1)
    KSTEP(8,  pbA, pbB, 8, 1, 1)
    KSTEP(9,  pbB, pbA, 8, 1, 1)
    KSTEP(10, pbA, pbB, 8, 1, 1)
    KSTEP(11, pbB, pbA, 8, 1, 1)
    KSTEP(12, pbA, pbB, 8, 1, 1)
    KSTEP(13, pbB, pbA, 8, 1, 1)
    KSTEP(14, pbA, pbB, 8, 1, 1)
    KSTEP(15, pbB, pbA, 8, 1, 1)
    KSTEP(16, pbA, pbB, 8, 1, 1)
    KSTEP(17, pbB, pbA, 8, 1, 1)
    KSTEP(18, pbA, pbB, 8, 1, 1)
    KSTEP(19, pbB, pbA, 8, 1, 1)
    KSTEP(20, pbA, pbB, 8, 1, 1)
    KSTEP(21, pbB, pbA, 6, 0, 1)
    KSTEP(22, pbA, pbB, 4, 0, 1)
    KSTEP(23, pbB, pbA, 0, 0, 0)
#undef KSTEP

    // Epilogue: out[m,n] = scale(b,s) * (acc + bv[n]); C/D: col=lane&15, row=(lane>>4)*4+reg
    float bvv[4];
    #pragma unroll
    for (int nr = 0; nr < 4; ++nr)
        bvv[nr] = bv[nt * 256 + w * 64 + nr * 16 + (lane & 15)];

    int ncol0 = nt * 256 + w * 64 + (lane & 15);
    #pragma unroll
    for (int mr = 0; mr < 4; ++mr) {
        #pragma unroll
        for (int rg = 0; rg < 4; ++rg) {
            int m = m_base + mr * 16 + ((lane >> 4) << 2) + rg;
            int b = m / 261;
            int s = m - b * 261;
            float h = hot[b];
            float scale = (s < IMG) ? h : (1.0f - h);
            float* orow = out + (size_t)m * OUTn + ncol0;
            #pragma unroll
            for (int nr = 0; nr < 4; ++nr)
                orow[nr * 16] = scale * (acc[mr][nr][rg] + bvv[nr]);
        }
    }
}

extern "C" void kernel_launch(void* const* d_in, const int* in_sizes, int n_in,
                              void* d_out, int out_size, void* d_ws, size_t ws_size,
                              hipStream_t stream) {
    const float* Q   = (const float*)d_in[0];
    const float* K   = (const float*)d_in[1];
    const float* V   = (const float*)d_in[2];
    const float* Wq  = (const float*)d_in[3];
    const float* bq  = (const float*)d_in[4];
    const float* Wk  = (const float*)d_in[5];
    const float* bk  = (const float*)d_in[6];
    const float* Wsw = (const float*)d_in[7];
    const float* bsw = (const float*)d_in[8];
    const float* Wv  = (const float*)d_in[9];
    const float* bv  = (const float*)d_in[10];

    float* out = (float*)d_out;
    char* ws = (char*)d_ws;
    float* hot = (float*)(ws + WS_HOT);
    unsigned short* wsB = (unsigned short*)(ws + WS_WB);

    hipLaunchKernelGGL(wv_convert, dim3((OUTn * Dd + 255) / 256), dim3(256), 0, stream, Wv, wsB);
    hipLaunchKernelGGL(scores_fused, dim3(Bn), dim3(512), 0, stream,
                       Q, K, Wq, bq, Wk, bk, Wsw, bsw, out + CTX_ELEMS, hot);
    hipLaunchKernelGGL(ctx_gemm, dim3((Mrows / 64) * 2), dim3(256), 0, stream, V, wsB, bv, hot, out);
}